// Round 5
// baseline (121.102 us; speedup 1.0000x reference)
//
#include <hip/hip_runtime.h>
#include <stdint.h>

typedef float f32x4 __attribute__((ext_vector_type(4)));
typedef short short8 __attribute__((ext_vector_type(8)));
typedef short short4v __attribute__((ext_vector_type(4)));

#define N_SPATIAL 65536   // 256*256
#define DIM 256
#define GROUPS 32
#define HIDDEN 128

__device__ __forceinline__ float b2f(uint16_t u) {
  union { uint32_t u; float f; } v; v.u = ((uint32_t)u) << 16; return v.f;
}
__device__ __forceinline__ uint16_t f2b(float f) {
  union { float f; uint32_t u; } v; v.f = f;
  uint32_t r = (v.u + 0x7FFFu + ((v.u >> 16) & 1u)) >> 16;
  return (uint16_t)r;
}

// ---------------------------------------------------------------------------
// K1: transpose x (c,n) fp32 -> xT (n,c) bf16, plus GroupNorm partial stats.
// grid 1024 (64-n tiles), block 256.
__global__ __launch_bounds__(256) void k1_transpose_stats(
    const float* __restrict__ x, uint16_t* __restrict__ xT, float* __restrict__ gnp) {
  __shared__ uint16_t xs[64][264];   // [n][c] padded stride 264
  const int t = threadIdx.x;
  const int n0 = blockIdx.x * 64;
  const int c_l = (t >> 2) & 15;
  const int nq  = (t & 3) + 4 * (t >> 6);
  for (int p = 0; p < 16; ++p) {
    int c = 16 * p + c_l;
    float4 v = *(const float4*)(x + (size_t)c * N_SPATIAL + n0 + nq * 4);
    int nn = nq * 4;
    xs[nn + 0][c] = f2b(v.x); xs[nn + 1][c] = f2b(v.y);
    xs[nn + 2][c] = f2b(v.z); xs[nn + 3][c] = f2b(v.w);
  }
  __syncthreads();
  {
    int g = t >> 3; int c = g * 8 + (t & 7);
    float s = 0.f, ss = 0.f;
    for (int n = 0; n < 64; ++n) { float f = b2f(xs[n][c]); s += f; ss += f * f; }
    s  += __shfl_xor(s, 1, 64);  ss += __shfl_xor(ss, 1, 64);
    s  += __shfl_xor(s, 2, 64);  ss += __shfl_xor(ss, 2, 64);
    s  += __shfl_xor(s, 4, 64);  ss += __shfl_xor(ss, 4, 64);
    if ((t & 7) == 0) {
      gnp[((size_t)blockIdx.x * 32 + g) * 2 + 0] = s;
      gnp[((size_t)blockIdx.x * 32 + g) * 2 + 1] = ss;
    }
  }
  for (int p = 0; p < 8; ++p) {
    int j = t + 256 * p; int n = j >> 5; int c16 = j & 31;
    f32x4 val = *(const f32x4*)((const char*)&xs[0][0] + n * 528 + c16 * 16);
    *(f32x4*)((char*)xT + ((size_t)(n0 + n)) * 512 + c16 * 16) = val;
  }
}

// ---------------------------------------------------------------------------
// K2f: merged stats-final + weight fold.  Each block (o = row of qkv_weight)
// redundantly reduces gnp (L2-resident) to group stats, derives per-channel
// a,b, then folds its weight row.  grid 384, block 256.
__global__ __launch_bounds__(256) void k2f_fold(
    const float* __restrict__ gnp, const float* __restrict__ gnw,
    const float* __restrict__ gnb, const float* __restrict__ qw,
    const float* __restrict__ qb, uint16_t* __restrict__ wp,
    float* __restrict__ biasp) {
  __shared__ float sred[4][32];
  __shared__ float ssred[4][32];
  __shared__ float sa[256], sb[256];
  __shared__ float rbias[4];
  const int o = blockIdx.x; const int t = threadIdx.x;
  const int g = t & 31, slice = t >> 5;
  float s = 0.f, ss = 0.f;
  for (int i = 0; i < 128; ++i) {
    int c = slice * 128 + i;
    s  += gnp[((size_t)c * 32 + g) * 2 + 0];
    ss += gnp[((size_t)c * 32 + g) * 2 + 1];
  }
  s += __shfl_xor(s, 32, 64); ss += __shfl_xor(ss, 32, 64);
  const int wv = t >> 6;
  if ((t & 63) < 32) { sred[wv][g] = s; ssred[wv][g] = ss; }
  __syncthreads();
  if (t < 32) {
    float S  = sred[0][t] + sred[1][t] + sred[2][t] + sred[3][t];
    float SS = ssred[0][t] + ssred[1][t] + ssred[2][t] + ssred[3][t];
    const float invN = 1.0f / 524288.0f;
    float mean = S * invN;
    float var  = SS * invN - mean * mean;
    float rs   = rsqrtf(var + 1e-5f);
    sred[0][t] = mean; ssred[0][t] = rs;
  }
  __syncthreads();
  {
    int gg = t >> 3;
    float aa = gnw[t] * ssred[0][gg];
    sa[t] = aa;
    sb[t] = gnb[t] - sred[0][gg] * aa;
  }
  __syncthreads();
  float w = qw[(size_t)o * 256 + t];
  wp[(size_t)o * 256 + t] = f2b(w * sa[t]);
  float p = w * sb[t];
  for (int m = 32; m >= 1; m >>= 1) p += __shfl_xor(p, m, 64);
  if ((t & 63) == 0) rbias[t >> 6] = p;
  __syncthreads();
  if (t == 0) biasp[o] = qb[o] + rbias[0] + rbias[1] + rbias[2] + rbias[3];
}

// ---------------------------------------------------------------------------
// K3kv: k,v GEMM (256 rows x 64 pixels, 2 subtiles/block) + in-block context.
// wave wid owns rows wid*64..+63 (wid 0,1 = k -> exp -> ek LDS; 2,3 = v).
// Context per wave = head via MFMA, accumulated in regs across subtiles.
// grid 512, block 256, LDS 40KB.
__global__ __launch_bounds__(256) void k3_kv(
    const uint16_t* __restrict__ xT, const uint16_t* __restrict__ wp,
    const float* __restrict__ biasp, float* __restrict__ part) {
  __shared__ __align__(16) char smem[40960]; // A[0,32K) B[32K,40K); ek[0,16K) v[16K,32K) reuse
  const int t = threadIdx.x;
  const int l = t & 63, wid = t >> 6;
  const int lrow = l & 15, lk = l >> 4;

  f32x4 cacc[2][2] = {};
  float denp[16];
  #pragma unroll
  for (int i = 0; i < 16; ++i) denp[i] = 0.f;

  for (int sub = 0; sub < 2; ++sub) {
    const int n0 = blockIdx.x * 128 + sub * 64;
    f32x4 acc[4][4] = {};
    for (int ks = 0; ks < 4; ++ks) {
      const int k0 = ks * 64;
      __syncthreads();
      #pragma unroll
      for (int p = 0; p < 8; ++p) {
        int flat = t + 256 * p;
        int row = flat >> 3, c = flat & 7;
        f32x4 va = *(const f32x4*)((const char*)wp + (size_t)(128 + row) * 512 + k0 * 2 + c * 16);
        *(f32x4*)(&smem[row * 128 + ((c ^ (row & 7)) << 4)]) = va;
      }
      #pragma unroll
      for (int p = 0; p < 2; ++p) {
        int flat = t + 256 * p;
        int row = flat >> 3, c = flat & 7;
        f32x4 vb = *(const f32x4*)((const char*)xT + (size_t)(n0 + row) * 512 + k0 * 2 + c * 16);
        *(f32x4*)(&smem[32768 + row * 128 + ((c ^ (row & 7)) << 4)]) = vb;
      }
      __syncthreads();
      #pragma unroll
      for (int kk = 0; kk < 2; ++kk) {
        short8 a[4], b[4];
        #pragma unroll
        for (int m = 0; m < 4; ++m) {
          int row = wid * 64 + m * 16 + lrow;
          a[m] = *(const short8*)(&smem[row * 128 + (((kk * 4 + lk) ^ (row & 7)) << 4)]);
        }
        #pragma unroll
        for (int n = 0; n < 4; ++n) {
          int row = n * 16 + lrow;
          b[n] = *(const short8*)(&smem[32768 + row * 128 + (((kk * 4 + lk) ^ (row & 7)) << 4)]);
        }
        #pragma unroll
        for (int m = 0; m < 4; ++m)
          #pragma unroll
          for (int n = 0; n < 4; ++n)
            acc[m][n] = __builtin_amdgcn_mfma_f32_16x16x32_bf16(a[m], b[n], acc[m][n], 0, 0, 0);
      }
    }
    __syncthreads();
    {
      const bool isk = wid < 2;
      const int base = isk ? 0 : 16384;
      #pragma unroll
      for (int m = 0; m < 4; ++m) {
        float bb[4];
        #pragma unroll
        for (int j = 0; j < 4; ++j) bb[j] = biasp[128 + wid * 64 + m * 16 + lk * 4 + j];
        #pragma unroll
        for (int n = 0; n < 4; ++n) {
          int col = n * 16 + lrow;
          int coff = col >> 3, cbyte = (col & 7) * 2;
          #pragma unroll
          for (int j = 0; j < 4; ++j) {
            int rloc = ((wid * 64) & 127) + m * 16 + lk * 4 + j;   // row within 128
            float val = acc[m][n][j] + bb[j];
            if (isk) { val = __expf(val); denp[m * 4 + j] += val; }
            *(uint16_t*)(&smem[base + rloc * 128 + ((coff ^ (rloc & 7)) << 4) + cbyte]) = f2b(val);
          }
        }
      }
    }
    __syncthreads();
    {
      const int h = wid;
      #pragma unroll
      for (int kw = 0; kw < 2; ++kw) {
        short8 ae[2], be[2];
        #pragma unroll
        for (int mf = 0; mf < 2; ++mf) {
          int row = h * 32 + mf * 16 + lrow;
          ae[mf] = *(const short8*)(&smem[row * 128 + (((kw * 4 + lk) ^ (row & 7)) << 4)]);
        }
        #pragma unroll
        for (int nf = 0; nf < 2; ++nf) {
          int row = h * 32 + nf * 16 + lrow;
          be[nf] = *(const short8*)(&smem[16384 + row * 128 + (((kw * 4 + lk) ^ (row & 7)) << 4)]);
        }
        #pragma unroll
        for (int mf = 0; mf < 2; ++mf)
          #pragma unroll
          for (int nf = 0; nf < 2; ++nf)
            cacc[mf][nf] = __builtin_amdgcn_mfma_f32_16x16x32_bf16(ae[mf], be[nf], cacc[mf][nf], 0, 0, 0);
      }
    }
  }
  float* pp = part + (size_t)blockIdx.x * 4224;
  {
    float* ph = pp + wid * 1056;
    #pragma unroll
    for (int mf = 0; mf < 2; ++mf)
      #pragma unroll
      for (int nf = 0; nf < 2; ++nf)
        #pragma unroll
        for (int j = 0; j < 4; ++j) {
          int d = mf * 16 + lk * 4 + j, e = nf * 16 + lrow;
          ph[d * 32 + e] = cacc[mf][nf][j];
        }
  }
  if (wid < 2) {
    #pragma unroll
    for (int i = 0; i < 16; ++i) {
      denp[i] += __shfl_xor(denp[i], 1, 64);
      denp[i] += __shfl_xor(denp[i], 2, 64);
      denp[i] += __shfl_xor(denp[i], 4, 64);
      denp[i] += __shfl_xor(denp[i], 8, 64);
    }
    if (lrow == 0) {
      #pragma unroll
      for (int m = 0; m < 4; ++m)
        #pragma unroll
        for (int j = 0; j < 4; ++j) {
          int r = wid * 64 + m * 16 + lk * 4 + j;   // 0..127 k-row
          pp[(r >> 5) * 1056 + 1024 + (r & 31)] = denp[m * 4 + j];
        }
    }
  }
}

// ---------------------------------------------------------------------------
// K6: reduce context partials over 512 blocks.  grid 17, block 256.
__global__ __launch_bounds__(256) void k6_reduce(
    const float* __restrict__ part, float* __restrict__ ctxs) {
  int id = blockIdx.x * 256 + threadIdx.x;
  if (id >= 4224) return;
  float s = 0.f;
  for (int c = 0; c < 512; ++c) s += part[(size_t)c * 4224 + id];
  ctxs[id] = s;
}

// ---------------------------------------------------------------------------
// KM: merged M-fold + M2-fold.  Per block (o = output row):
//  phase A: Mrow[d] = sum_e ow[o][h*32+e]*ctx[h][d][e] / den[h][d]
//  phase B: M2[o][c] = sum_d Mrow[d]*Wq'[d][c]; bias2[o] = ob[o] + Mrow·bq'.
// grid 256, block 256.
__global__ __launch_bounds__(256) void kM_fold(
    const float* __restrict__ ow, const float* __restrict__ ctxs,
    const uint16_t* __restrict__ wp, const float* __restrict__ biasp,
    const float* __restrict__ ob, uint16_t* __restrict__ M2,
    float* __restrict__ bias2) {
  __shared__ float sctx[4224];
  __shared__ float sow[128];
  __shared__ float smrow[128];
  __shared__ float rb[4];
  const int o = blockIdx.x; const int t = threadIdx.x;
  for (int i = t; i < 4224; i += 256) sctx[i] = ctxs[i];
  if (t < 128) sow[t] = ow[(size_t)o * 128 + t];
  __syncthreads();
  if (t < 128) {
    int h = t >> 5, d = t & 31;
    const float* cs = sctx + h * 1056;
    float den = cs[1024 + d];
    float s = 0.f;
    #pragma unroll
    for (int e = 0; e < 32; ++e) {
      int er = (e + d) & 31;             // rotated start: bank-conflict-free
      s += sow[h * 32 + er] * cs[d * 32 + er];
    }
    smrow[t] = s / den;
  }
  __syncthreads();
  float acc = 0.f;
  for (int d = 0; d < 128; ++d) acc += smrow[d] * b2f(wp[(size_t)d * 256 + t]);
  M2[(size_t)o * 256 + t] = f2b(acc);
  float p = (t < 128) ? smrow[t] * biasp[t] : 0.f;
  for (int m = 32; m >= 1; m >>= 1) p += __shfl_xor(p, m, 64);
  if ((t & 63) == 0) rb[t >> 6] = p;
  __syncthreads();
  if (t == 0) bias2[o] = ob[o] + rb[0] + rb[1] + rb[2] + rb[3];
}

// ---------------------------------------------------------------------------
// K7: out = M2(256x256 bf16) @ xT + bias2.  BM=128, BN=128, K=256.
// 32KB LDS; output staged in two 64-row halves for 512B coalesced stores.
// grid 1024, block 256.
__global__ __launch_bounds__(256) void k7_out(
    const uint16_t* __restrict__ xT, const uint16_t* __restrict__ M2,
    const float* __restrict__ bias2, float* __restrict__ out) {
  __shared__ __align__(16) char smem[32768];
  const int t = threadIdx.x;
  const int mt = blockIdx.x & 1, nt = blockIdx.x >> 1;
  const int o0 = mt * 128, n0 = nt * 128;
  const int l = t & 63, wid = t >> 6, wr = wid >> 1, wc = wid & 1;
  const int lrow = l & 15, lk = l >> 4;

  f32x4 acc[4][4] = {};
  for (int ks = 0; ks < 4; ++ks) {
    const int k0 = ks * 64;
    __syncthreads();
    #pragma unroll
    for (int p = 0; p < 4; ++p) {
      int flat = t + 256 * p;
      int row = flat >> 3, c = flat & 7;
      f32x4 va = *(const f32x4*)((const char*)M2 + (size_t)(o0 + row) * 512 + k0 * 2 + c * 16);
      *(f32x4*)(&smem[row * 128 + ((c ^ (row & 7)) << 4)]) = va;
      f32x4 vb = *(const f32x4*)((const char*)xT + (size_t)(n0 + row) * 512 + k0 * 2 + c * 16);
      *(f32x4*)(&smem[16384 + row * 128 + ((c ^ (row & 7)) << 4)]) = vb;
    }
    __syncthreads();
    #pragma unroll
    for (int kk = 0; kk < 2; ++kk) {
      short8 a[4], b[4];
      #pragma unroll
      for (int m = 0; m < 4; ++m) {
        int row = wr * 64 + m * 16 + lrow;
        a[m] = *(const short8*)(&smem[row * 128 + (((kk * 4 + lk) ^ (row & 7)) << 4)]);
      }
      #pragma unroll
      for (int n = 0; n < 4; ++n) {
        int row = wc * 64 + n * 16 + lrow;
        b[n] = *(const short8*)(&smem[16384 + row * 128 + (((kk * 4 + lk) ^ (row & 7)) << 4)]);
      }
      #pragma unroll
      for (int m = 0; m < 4; ++m)
        #pragma unroll
        for (int n = 0; n < 4; ++n)
          acc[m][n] = __builtin_amdgcn_mfma_f32_16x16x32_bf16(a[m], b[n], acc[m][n], 0, 0, 0);
    }
  }

  #pragma unroll
  for (int half = 0; half < 2; ++half) {
    __syncthreads();
    if (wr == half) {
      #pragma unroll
      for (int m = 0; m < 4; ++m) {
        int rb = m * 16 + lk * 4;
        float bb[4];
        #pragma unroll
        for (int j = 0; j < 4; ++j) bb[j] = bias2[o0 + half * 64 + rb + j];
        #pragma unroll
        for (int n = 0; n < 4; ++n) {
          int col = wc * 64 + n * 16 + lrow;
          #pragma unroll
          for (int j = 0; j < 4; ++j) {
            int row = rb + j;
            *(float*)(&smem[row * 512 + ((((col >> 2) ^ (row & 7)) << 4)) + (col & 3) * 4]) =
                acc[m][n][j] + bb[j];
          }
        }
      }
    }
    __syncthreads();
    #pragma unroll
    for (int p = 0; p < 8; ++p) {
      int flat = t + 256 * p; int row = flat >> 5, c = flat & 31;
      f32x4 v = *(const f32x4*)(&smem[row * 512 + (((c ^ (row & 7)) << 4))]);
      *(f32x4*)(out + (size_t)(o0 + half * 64 + row) * N_SPATIAL + n0 + c * 4) = v;
    }
  }
}

// ---------------------------------------------------------------------------
extern "C" void kernel_launch(void* const* d_in, const int* in_sizes, int n_in,
                              void* d_out, int out_size, void* d_ws, size_t ws_size,
                              hipStream_t stream) {
  const float* x   = (const float*)d_in[0];
  const float* gnw = (const float*)d_in[1];
  const float* gnb = (const float*)d_in[2];
  const float* qw  = (const float*)d_in[3];
  const float* qb  = (const float*)d_in[4];
  const float* ow  = (const float*)d_in[5];
  const float* ob  = (const float*)d_in[6];
  float* out = (float*)d_out;
  char* ws = (char*)d_ws;

  uint16_t* xT    = (uint16_t*)(ws + 0);          // 32 MB
  uint16_t* wp    = (uint16_t*)(ws + 33554432);   // 192 KB
  float*    biasp = (float*)   (ws + 33751040);   // 1.5 KB
  float*    gnp   = (float*)   (ws + 33754624);   // 256 KB
  float*    part  = (float*)   (ws + 34016768);   // 8.65 MB (512*4224*4)
  float*    ctxs  = (float*)   (ws + 42667520);   // 16.9 KB
  uint16_t* M2    = (uint16_t*)(ws + 42815488);   // 128 KB
  float*    bias2 = (float*)   (ws + 42946560);   // 1 KB

  k1_transpose_stats<<<dim3(1024), dim3(256), 0, stream>>>(x, xT, gnp);
  k2f_fold<<<dim3(384), dim3(256), 0, stream>>>(gnp, gnw, gnb, qw, qb, wp, biasp);
  k3_kv<<<dim3(512), dim3(256), 0, stream>>>(xT, wp, biasp, part);
  k6_reduce<<<dim3(17), dim3(256), 0, stream>>>(part, ctxs);
  kM_fold<<<dim3(256), dim3(256), 0, stream>>>(ow, ctxs, wp, biasp, ob, M2, bias2);
  k7_out<<<dim3(1024), dim3(256), 0, stream>>>(xT, M2, bias2, out);
}

// Round 6
// 93.606 us; speedup vs baseline: 1.2937x; 1.2937x over previous
//
#include <hip/hip_runtime.h>
#include <stdint.h>

typedef float f32x4 __attribute__((ext_vector_type(4)));
typedef short short8 __attribute__((ext_vector_type(8)));
typedef short short4v __attribute__((ext_vector_type(4)));

#define N_SPATIAL 65536   // 256*256
#define DIM 256
#define GROUPS 32
#define HIDDEN 128

__device__ __forceinline__ float b2f(uint16_t u) {
  union { uint32_t u; float f; } v; v.u = ((uint32_t)u) << 16; return v.f;
}
__device__ __forceinline__ uint16_t f2b(float f) {
  union { float f; uint32_t u; } v; v.f = f;
  uint32_t r = (v.u + 0x7FFFu + ((v.u >> 16) & 1u)) >> 16;
  return (uint16_t)r;
}

// ---------------------------------------------------------------------------
// K1: transpose x (c,n) fp32 -> xT (n,c) bf16, plus GroupNorm partial stats.
// grid 1024 (64-n tiles), block 256.
__global__ __launch_bounds__(256) void k1_transpose_stats(
    const float* __restrict__ x, uint16_t* __restrict__ xT, float* __restrict__ gnp) {
  __shared__ uint16_t xs[64][264];   // [n][c] padded stride 264
  const int t = threadIdx.x;
  const int n0 = blockIdx.x * 64;
  const int c_l = (t >> 2) & 15;
  const int nq  = (t & 3) + 4 * (t >> 6);
  for (int p = 0; p < 16; ++p) {
    int c = 16 * p + c_l;
    float4 v = *(const float4*)(x + (size_t)c * N_SPATIAL + n0 + nq * 4);
    int nn = nq * 4;
    xs[nn + 0][c] = f2b(v.x); xs[nn + 1][c] = f2b(v.y);
    xs[nn + 2][c] = f2b(v.z); xs[nn + 3][c] = f2b(v.w);
  }
  __syncthreads();
  {
    int g = t >> 3; int c = g * 8 + (t & 7);
    float s = 0.f, ss = 0.f;
    for (int n = 0; n < 64; ++n) { float f = b2f(xs[n][c]); s += f; ss += f * f; }
    s  += __shfl_xor(s, 1, 64);  ss += __shfl_xor(ss, 1, 64);
    s  += __shfl_xor(s, 2, 64);  ss += __shfl_xor(ss, 2, 64);
    s  += __shfl_xor(s, 4, 64);  ss += __shfl_xor(ss, 4, 64);
    if ((t & 7) == 0) {
      gnp[((size_t)blockIdx.x * 32 + g) * 2 + 0] = s;
      gnp[((size_t)blockIdx.x * 32 + g) * 2 + 1] = ss;
    }
  }
  for (int p = 0; p < 8; ++p) {
    int j = t + 256 * p; int n = j >> 5; int c16 = j & 31;
    f32x4 val = *(const f32x4*)((const char*)&xs[0][0] + n * 528 + c16 * 16);
    *(f32x4*)((char*)xT + ((size_t)(n0 + n)) * 512 + c16 * 16) = val;
  }
}

// ---------------------------------------------------------------------------
// K2f: merged stats-final + weight fold.  grid 384, block 256.
__global__ __launch_bounds__(256) void k2f_fold(
    const float* __restrict__ gnp, const float* __restrict__ gnw,
    const float* __restrict__ gnb, const float* __restrict__ qw,
    const float* __restrict__ qb, uint16_t* __restrict__ wp,
    float* __restrict__ biasp) {
  __shared__ float sred[4][32];
  __shared__ float ssred[4][32];
  __shared__ float sa[256], sb[256];
  __shared__ float rbias[4];
  const int o = blockIdx.x; const int t = threadIdx.x;
  const int g = t & 31, slice = t >> 5;
  float s = 0.f, ss = 0.f;
  for (int i = 0; i < 128; ++i) {
    int c = slice * 128 + i;
    s  += gnp[((size_t)c * 32 + g) * 2 + 0];
    ss += gnp[((size_t)c * 32 + g) * 2 + 1];
  }
  s += __shfl_xor(s, 32, 64); ss += __shfl_xor(ss, 32, 64);
  const int wv = t >> 6;
  if ((t & 63) < 32) { sred[wv][g] = s; ssred[wv][g] = ss; }
  __syncthreads();
  if (t < 32) {
    float S  = sred[0][t] + sred[1][t] + sred[2][t] + sred[3][t];
    float SS = ssred[0][t] + ssred[1][t] + ssred[2][t] + ssred[3][t];
    const float invN = 1.0f / 524288.0f;
    float mean = S * invN;
    float var  = SS * invN - mean * mean;
    float rs   = rsqrtf(var + 1e-5f);
    sred[0][t] = mean; ssred[0][t] = rs;
  }
  __syncthreads();
  {
    int gg = t >> 3;
    float aa = gnw[t] * ssred[0][gg];
    sa[t] = aa;
    sb[t] = gnb[t] - sred[0][gg] * aa;
  }
  __syncthreads();
  float w = qw[(size_t)o * 256 + t];
  wp[(size_t)o * 256 + t] = f2b(w * sa[t]);
  float p = w * sb[t];
  for (int m = 32; m >= 1; m >>= 1) p += __shfl_xor(p, m, 64);
  if ((t & 63) == 0) rbias[t >> 6] = p;
  __syncthreads();
  if (t == 0) biasp[o] = qb[o] + rbias[0] + rbias[1] + rbias[2] + rbias[3];
}

// ---------------------------------------------------------------------------
// K3kv v2: k,v GEMM (256 rows x 64 pixels per block) + in-block context.
// grid 1024 (one 64-pixel tile per block) -> 11 barriers/block (was 26),
// better cross-block overlap.  wave wid owns W-rows wid*64..+63
// (wid 0,1 = k -> exp -> ek LDS; wid 2,3 = v -> LDS).  Context per
// wave = head via MFMA.  block 256, LDS 40KB (~3 blocks/CU by VGPR).
__global__ __launch_bounds__(256) void k3_kv(
    const uint16_t* __restrict__ xT, const uint16_t* __restrict__ wp,
    const float* __restrict__ biasp, float* __restrict__ part) {
  __shared__ __align__(16) char smem[40960]; // A[0,32K) B[32K,40K); ek[0,16K) v[16K,32K) reuse
  const int t = threadIdx.x;
  const int l = t & 63, wid = t >> 6;
  const int lrow = l & 15, lk = l >> 4;

  const int n0 = blockIdx.x * 64;
  f32x4 acc[4][4] = {};
  for (int ks = 0; ks < 4; ++ks) {
    const int k0 = ks * 64;
    __syncthreads();
    #pragma unroll
    for (int p = 0; p < 8; ++p) {
      int flat = t + 256 * p;
      int row = flat >> 3, c = flat & 7;
      f32x4 va = *(const f32x4*)((const char*)wp + (size_t)(128 + row) * 512 + k0 * 2 + c * 16);
      *(f32x4*)(&smem[row * 128 + ((c ^ (row & 7)) << 4)]) = va;
    }
    #pragma unroll
    for (int p = 0; p < 2; ++p) {
      int flat = t + 256 * p;
      int row = flat >> 3, c = flat & 7;
      f32x4 vb = *(const f32x4*)((const char*)xT + (size_t)(n0 + row) * 512 + k0 * 2 + c * 16);
      *(f32x4*)(&smem[32768 + row * 128 + ((c ^ (row & 7)) << 4)]) = vb;
    }
    __syncthreads();
    #pragma unroll
    for (int kk = 0; kk < 2; ++kk) {
      short8 a[4], b[4];
      #pragma unroll
      for (int m = 0; m < 4; ++m) {
        int row = wid * 64 + m * 16 + lrow;
        a[m] = *(const short8*)(&smem[row * 128 + (((kk * 4 + lk) ^ (row & 7)) << 4)]);
      }
      #pragma unroll
      for (int n = 0; n < 4; ++n) {
        int row = n * 16 + lrow;
        b[n] = *(const short8*)(&smem[32768 + row * 128 + (((kk * 4 + lk) ^ (row & 7)) << 4)]);
      }
      #pragma unroll
      for (int m = 0; m < 4; ++m)
        #pragma unroll
        for (int n = 0; n < 4; ++n)
          acc[m][n] = __builtin_amdgcn_mfma_f32_16x16x32_bf16(a[m], b[n], acc[m][n], 0, 0, 0);
    }
  }
  __syncthreads();

  float denp[16];
  #pragma unroll
  for (int i = 0; i < 16; ++i) denp[i] = 0.f;
  {
    const bool isk = wid < 2;
    const int base = isk ? 0 : 16384;
    #pragma unroll
    for (int m = 0; m < 4; ++m) {
      float bb[4];
      #pragma unroll
      for (int j = 0; j < 4; ++j) bb[j] = biasp[128 + wid * 64 + m * 16 + lk * 4 + j];
      #pragma unroll
      for (int n = 0; n < 4; ++n) {
        int col = n * 16 + lrow;
        int coff = col >> 3, cbyte = (col & 7) * 2;
        #pragma unroll
        for (int j = 0; j < 4; ++j) {
          int rloc = ((wid * 64) & 127) + m * 16 + lk * 4 + j;   // row within 128
          float val = acc[m][n][j] + bb[j];
          if (isk) { val = __expf(val); denp[m * 4 + j] += val; }
          *(uint16_t*)(&smem[base + rloc * 128 + ((coff ^ (rloc & 7)) << 4) + cbyte]) = f2b(val);
        }
      }
    }
  }
  __syncthreads();

  f32x4 cacc[2][2] = {};
  {
    const int h = wid;
    #pragma unroll
    for (int kw = 0; kw < 2; ++kw) {
      short8 ae[2], be[2];
      #pragma unroll
      for (int mf = 0; mf < 2; ++mf) {
        int row = h * 32 + mf * 16 + lrow;
        ae[mf] = *(const short8*)(&smem[row * 128 + (((kw * 4 + lk) ^ (row & 7)) << 4)]);
      }
      #pragma unroll
      for (int nf = 0; nf < 2; ++nf) {
        int row = h * 32 + nf * 16 + lrow;
        be[nf] = *(const short8*)(&smem[16384 + row * 128 + (((kw * 4 + lk) ^ (row & 7)) << 4)]);
      }
      #pragma unroll
      for (int mf = 0; mf < 2; ++mf)
        #pragma unroll
        for (int nf = 0; nf < 2; ++nf)
          cacc[mf][nf] = __builtin_amdgcn_mfma_f32_16x16x32_bf16(ae[mf], be[nf], cacc[mf][nf], 0, 0, 0);
    }
  }
  float* pp = part + (size_t)blockIdx.x * 4224;
  {
    float* ph = pp + wid * 1056;
    #pragma unroll
    for (int mf = 0; mf < 2; ++mf)
      #pragma unroll
      for (int nf = 0; nf < 2; ++nf)
        #pragma unroll
        for (int j = 0; j < 4; ++j) {
          int d = mf * 16 + lk * 4 + j, e = nf * 16 + lrow;
          ph[d * 32 + e] = cacc[mf][nf][j];
        }
  }
  if (wid < 2) {
    #pragma unroll
    for (int i = 0; i < 16; ++i) {
      denp[i] += __shfl_xor(denp[i], 1, 64);
      denp[i] += __shfl_xor(denp[i], 2, 64);
      denp[i] += __shfl_xor(denp[i], 4, 64);
      denp[i] += __shfl_xor(denp[i], 8, 64);
    }
    if (lrow == 0) {
      #pragma unroll
      for (int m = 0; m < 4; ++m)
        #pragma unroll
        for (int j = 0; j < 4; ++j) {
          int r = wid * 64 + m * 16 + lk * 4 + j;   // 0..127 k-row
          pp[(r >> 5) * 1056 + 1024 + (r & 31)] = denp[m * 4 + j];
        }
    }
  }
}

// ---------------------------------------------------------------------------
// K6 v2: reduce context partials over 1024 blocks, 8-way parallel over
// c-chunks.  grid 136 = 17 id-blocks x 8 chunks of 128.  Writes part2[8][4224].
__global__ __launch_bounds__(256) void k6_reduce(
    const float* __restrict__ part, float* __restrict__ part2) {
  const int bx = blockIdx.x;
  const int idb = bx % 17, cg = bx / 17;
  const int id = idb * 256 + threadIdx.x;
  if (id >= 4224) return;
  const float* p = part + (size_t)cg * 128 * 4224 + id;
  float s0 = 0.f, s1 = 0.f, s2 = 0.f, s3 = 0.f;
  for (int c = 0; c < 128; c += 4) {
    s0 += p[(size_t)(c + 0) * 4224];
    s1 += p[(size_t)(c + 1) * 4224];
    s2 += p[(size_t)(c + 2) * 4224];
    s3 += p[(size_t)(c + 3) * 4224];
  }
  part2[cg * 4224 + id] = (s0 + s1) + (s2 + s3);
}

// ---------------------------------------------------------------------------
// KM: merged M-fold + M2-fold (sums the 8 part2 chunks on load).
// grid 256, block 256.
__global__ __launch_bounds__(256) void kM_fold(
    const float* __restrict__ ow, const float* __restrict__ part2,
    const uint16_t* __restrict__ wp, const float* __restrict__ biasp,
    const float* __restrict__ ob, uint16_t* __restrict__ M2,
    float* __restrict__ bias2) {
  __shared__ float sctx[4224];
  __shared__ float sow[128];
  __shared__ float smrow[128];
  __shared__ float rb[4];
  const int o = blockIdx.x; const int t = threadIdx.x;
  for (int i = t; i < 4224; i += 256) {
    float s = 0.f;
    #pragma unroll
    for (int g = 0; g < 8; ++g) s += part2[g * 4224 + i];
    sctx[i] = s;
  }
  if (t < 128) sow[t] = ow[(size_t)o * 128 + t];
  __syncthreads();
  if (t < 128) {
    int h = t >> 5, d = t & 31;
    const float* cs = sctx + h * 1056;
    float den = cs[1024 + d];
    float s = 0.f;
    #pragma unroll
    for (int e = 0; e < 32; ++e) {
      int er = (e + d) & 31;             // rotated start: bank-conflict-free
      s += sow[h * 32 + er] * cs[d * 32 + er];
    }
    smrow[t] = s / den;
  }
  __syncthreads();
  float acc = 0.f;
  for (int d = 0; d < 128; ++d) acc += smrow[d] * b2f(wp[(size_t)d * 256 + t]);
  M2[(size_t)o * 256 + t] = f2b(acc);
  float p = (t < 128) ? smrow[t] * biasp[t] : 0.f;
  for (int m = 32; m >= 1; m >>= 1) p += __shfl_xor(p, m, 64);
  if ((t & 63) == 0) rb[t >> 6] = p;
  __syncthreads();
  if (t == 0) bias2[o] = ob[o] + rb[0] + rb[1] + rb[2] + rb[3];
}

// ---------------------------------------------------------------------------
// K7: out = M2(256x256 bf16) @ xT + bias2.  BM=128, BN=128, K=256.
// 32KB LDS; output staged in two 64-row halves for 512B coalesced stores.
// grid 1024, block 256.
__global__ __launch_bounds__(256) void k7_out(
    const uint16_t* __restrict__ xT, const uint16_t* __restrict__ M2,
    const float* __restrict__ bias2, float* __restrict__ out) {
  __shared__ __align__(16) char smem[32768];
  const int t = threadIdx.x;
  const int mt = blockIdx.x & 1, nt = blockIdx.x >> 1;
  const int o0 = mt * 128, n0 = nt * 128;
  const int l = t & 63, wid = t >> 6, wr = wid >> 1, wc = wid & 1;
  const int lrow = l & 15, lk = l >> 4;

  f32x4 acc[4][4] = {};
  for (int ks = 0; ks < 4; ++ks) {
    const int k0 = ks * 64;
    __syncthreads();
    #pragma unroll
    for (int p = 0; p < 4; ++p) {
      int flat = t + 256 * p;
      int row = flat >> 3, c = flat & 7;
      f32x4 va = *(const f32x4*)((const char*)M2 + (size_t)(o0 + row) * 512 + k0 * 2 + c * 16);
      *(f32x4*)(&smem[row * 128 + ((c ^ (row & 7)) << 4)]) = va;
      f32x4 vb = *(const f32x4*)((const char*)xT + (size_t)(n0 + row) * 512 + k0 * 2 + c * 16);
      *(f32x4*)(&smem[16384 + row * 128 + ((c ^ (row & 7)) << 4)]) = vb;
    }
    __syncthreads();
    #pragma unroll
    for (int kk = 0; kk < 2; ++kk) {
      short8 a[4], b[4];
      #pragma unroll
      for (int m = 0; m < 4; ++m) {
        int row = wr * 64 + m * 16 + lrow;
        a[m] = *(const short8*)(&smem[row * 128 + (((kk * 4 + lk) ^ (row & 7)) << 4)]);
      }
      #pragma unroll
      for (int n = 0; n < 4; ++n) {
        int row = wc * 64 + n * 16 + lrow;
        b[n] = *(const short8*)(&smem[16384 + row * 128 + (((kk * 4 + lk) ^ (row & 7)) << 4)]);
      }
      #pragma unroll
      for (int m = 0; m < 4; ++m)
        #pragma unroll
        for (int n = 0; n < 4; ++n)
          acc[m][n] = __builtin_amdgcn_mfma_f32_16x16x32_bf16(a[m], b[n], acc[m][n], 0, 0, 0);
    }
  }

  #pragma unroll
  for (int half = 0; half < 2; ++half) {
    __syncthreads();
    if (wr == half) {
      #pragma unroll
      for (int m = 0; m < 4; ++m) {
        int rb = m * 16 + lk * 4;
        float bb[4];
        #pragma unroll
        for (int j = 0; j < 4; ++j) bb[j] = bias2[o0 + half * 64 + rb + j];
        #pragma unroll
        for (int n = 0; n < 4; ++n) {
          int col = wc * 64 + n * 16 + lrow;
          #pragma unroll
          for (int j = 0; j < 4; ++j) {
            int row = rb + j;
            *(float*)(&smem[row * 512 + ((((col >> 2) ^ (row & 7)) << 4)) + (col & 3) * 4]) =
                acc[m][n][j] + bb[j];
          }
        }
      }
    }
    __syncthreads();
    #pragma unroll
    for (int p = 0; p < 8; ++p) {
      int flat = t + 256 * p; int row = flat >> 5, c = flat & 31;
      f32x4 v = *(const f32x4*)(&smem[row * 512 + (((c ^ (row & 7)) << 4))]);
      *(f32x4*)(out + (size_t)(o0 + half * 64 + row) * N_SPATIAL + n0 + c * 4) = v;
    }
  }
}

// ---------------------------------------------------------------------------
extern "C" void kernel_launch(void* const* d_in, const int* in_sizes, int n_in,
                              void* d_out, int out_size, void* d_ws, size_t ws_size,
                              hipStream_t stream) {
  const float* x   = (const float*)d_in[0];
  const float* gnw = (const float*)d_in[1];
  const float* gnb = (const float*)d_in[2];
  const float* qw  = (const float*)d_in[3];
  const float* qb  = (const float*)d_in[4];
  const float* ow  = (const float*)d_in[5];
  const float* ob  = (const float*)d_in[6];
  float* out = (float*)d_out;
  char* ws = (char*)d_ws;

  uint16_t* xT    = (uint16_t*)(ws + 0);          // 32 MB
  uint16_t* wp    = (uint16_t*)(ws + 33554432);   // 192 KB
  float*    biasp = (float*)   (ws + 33751040);   // 1.5 KB
  float*    gnp   = (float*)   (ws + 33752576);   // 256 KB
  float*    part  = (float*)   (ws + 34014720);   // 17.3 MB (1024*4224*4)
  float*    part2 = (float*)   (ws + 51316224);   // 132 KB (8*4224*4)
  uint16_t* M2    = (uint16_t*)(ws + 51451392);   // 128 KB
  float*    bias2 = (float*)   (ws + 51582464);   // 1 KB

  k1_transpose_stats<<<dim3(1024), dim3(256), 0, stream>>>(x, xT, gnp);
  k2f_fold<<<dim3(384), dim3(256), 0, stream>>>(gnp, gnw, gnb, qw, qb, wp, biasp);
  k3_kv<<<dim3(1024), dim3(256), 0, stream>>>(xT, wp, biasp, part);
  k6_reduce<<<dim3(136), dim3(256), 0, stream>>>(part, part2);
  kM_fold<<<dim3(256), dim3(256), 0, stream>>>(ow, part2, wp, biasp, ob, M2, bias2);
  k7_out<<<dim3(1024), dim3(256), 0, stream>>>(xT, M2, bias2, out);
}

// Round 7
// 92.462 us; speedup vs baseline: 1.3098x; 1.0124x over previous
//
#include <hip/hip_runtime.h>
#include <stdint.h>

typedef float f32x4 __attribute__((ext_vector_type(4)));
typedef short short8 __attribute__((ext_vector_type(8)));
typedef short short4v __attribute__((ext_vector_type(4)));

#define N_SPATIAL 65536   // 256*256
#define DIM 256
#define GROUPS 32
#define HIDDEN 128

__device__ __forceinline__ float b2f(uint16_t u) {
  union { uint32_t u; float f; } v; v.u = ((uint32_t)u) << 16; return v.f;
}
__device__ __forceinline__ uint16_t f2b(float f) {
  union { float f; uint32_t u; } v; v.f = f;
  uint32_t r = (v.u + 0x7FFFu + ((v.u >> 16) & 1u)) >> 16;
  return (uint16_t)r;
}

// async 16B global -> LDS (direct, no VGPR round-trip).  LDS dest must be
// wave-uniform base; HW adds lane*16.  Source addr is per-lane.
__device__ __forceinline__ void async16(const void* g, void* l) {
  __builtin_amdgcn_global_load_lds(
      (__attribute__((address_space(1))) void*)g,
      (__attribute__((address_space(3))) void*)l, 16, 0, 0);
}

// ---------------------------------------------------------------------------
// K1: transpose x (c,n) fp32 -> xT (n,c) bf16, plus GroupNorm partial stats.
// grid 1024 (64-n tiles), block 256.
__global__ __launch_bounds__(256) void k1_transpose_stats(
    const float* __restrict__ x, uint16_t* __restrict__ xT, float* __restrict__ gnp) {
  __shared__ uint16_t xs[64][264];   // [n][c] padded stride 264
  const int t = threadIdx.x;
  const int n0 = blockIdx.x * 64;
  const int c_l = (t >> 2) & 15;
  const int nq  = (t & 3) + 4 * (t >> 6);
  for (int p = 0; p < 16; ++p) {
    int c = 16 * p + c_l;
    float4 v = *(const float4*)(x + (size_t)c * N_SPATIAL + n0 + nq * 4);
    int nn = nq * 4;
    xs[nn + 0][c] = f2b(v.x); xs[nn + 1][c] = f2b(v.y);
    xs[nn + 2][c] = f2b(v.z); xs[nn + 3][c] = f2b(v.w);
  }
  __syncthreads();
  {
    int g = t >> 3; int c = g * 8 + (t & 7);
    float s = 0.f, ss = 0.f;
    for (int n = 0; n < 64; ++n) { float f = b2f(xs[n][c]); s += f; ss += f * f; }
    s  += __shfl_xor(s, 1, 64);  ss += __shfl_xor(ss, 1, 64);
    s  += __shfl_xor(s, 2, 64);  ss += __shfl_xor(ss, 2, 64);
    s  += __shfl_xor(s, 4, 64);  ss += __shfl_xor(ss, 4, 64);
    if ((t & 7) == 0) {
      gnp[((size_t)blockIdx.x * 32 + g) * 2 + 0] = s;
      gnp[((size_t)blockIdx.x * 32 + g) * 2 + 1] = ss;
    }
  }
  for (int p = 0; p < 8; ++p) {
    int j = t + 256 * p; int n = j >> 5; int c16 = j & 31;
    f32x4 val = *(const f32x4*)((const char*)&xs[0][0] + n * 528 + c16 * 16);
    *(f32x4*)((char*)xT + ((size_t)(n0 + n)) * 512 + c16 * 16) = val;
  }
}

// ---------------------------------------------------------------------------
// K2f: merged stats-final + weight fold.  grid 384, block 256.
__global__ __launch_bounds__(256) void k2f_fold(
    const float* __restrict__ gnp, const float* __restrict__ gnw,
    const float* __restrict__ gnb, const float* __restrict__ qw,
    const float* __restrict__ qb, uint16_t* __restrict__ wp,
    float* __restrict__ biasp) {
  __shared__ float sred[4][32];
  __shared__ float ssred[4][32];
  __shared__ float sa[256], sb[256];
  __shared__ float rbias[4];
  const int o = blockIdx.x; const int t = threadIdx.x;
  const int g = t & 31, slice = t >> 5;
  float s = 0.f, ss = 0.f;
  for (int i = 0; i < 128; ++i) {
    int c = slice * 128 + i;
    s  += gnp[((size_t)c * 32 + g) * 2 + 0];
    ss += gnp[((size_t)c * 32 + g) * 2 + 1];
  }
  s += __shfl_xor(s, 32, 64); ss += __shfl_xor(ss, 32, 64);
  const int wv = t >> 6;
  if ((t & 63) < 32) { sred[wv][g] = s; ssred[wv][g] = ss; }
  __syncthreads();
  if (t < 32) {
    float S  = sred[0][t] + sred[1][t] + sred[2][t] + sred[3][t];
    float SS = ssred[0][t] + ssred[1][t] + ssred[2][t] + ssred[3][t];
    const float invN = 1.0f / 524288.0f;
    float mean = S * invN;
    float var  = SS * invN - mean * mean;
    float rs   = rsqrtf(var + 1e-5f);
    sred[0][t] = mean; ssred[0][t] = rs;
  }
  __syncthreads();
  {
    int gg = t >> 3;
    float aa = gnw[t] * ssred[0][gg];
    sa[t] = aa;
    sb[t] = gnb[t] - sred[0][gg] * aa;
  }
  __syncthreads();
  float w = qw[(size_t)o * 256 + t];
  wp[(size_t)o * 256 + t] = f2b(w * sa[t]);
  float p = w * sb[t];
  for (int m = 32; m >= 1; m >>= 1) p += __shfl_xor(p, m, 64);
  if ((t & 63) == 0) rbias[t >> 6] = p;
  __syncthreads();
  if (t == 0) biasp[o] = qb[o] + rbias[0] + rbias[1] + rbias[2] + rbias[3];
}

// ---------------------------------------------------------------------------
// K3kv v3: identical structure to v2 but staging via async global_load_lds
// (linear LDS dest, inverse-XOR-swizzled per-lane global source; ds_read
// side unchanged -> staged bytes bit-identical).  grid 1024, block 256.
__global__ __launch_bounds__(256) void k3_kv(
    const uint16_t* __restrict__ xT, const uint16_t* __restrict__ wp,
    const float* __restrict__ biasp, float* __restrict__ part) {
  __shared__ __align__(16) char smem[40960]; // A[0,32K) B[32K,40K); ek[0,16K) v[16K,32K) reuse
  const int t = threadIdx.x;
  const int l = t & 63, wid = t >> 6;
  const int lrow = l & 15, lk = l >> 4;

  const int n0 = blockIdx.x * 64;
  f32x4 acc[4][4] = {};
  for (int ks = 0; ks < 4; ++ks) {
    const int k0 = ks * 64;
    __syncthreads();
    // W-slice: 2048 slots of 16B, linear LDS [0,32K)
    #pragma unroll
    for (int it = 0; it < 8; ++it) {
      int s = it * 256 + t;
      int row = s >> 3, c = s & 7;
      const char* gsrc = (const char*)wp + (size_t)(128 + row) * 512 + k0 * 2 + ((c ^ (row & 7)) << 4);
      async16(gsrc, smem + (s & ~63) * 16);
    }
    // xT-slice: 512 slots of 16B, linear LDS [32K,40K)
    #pragma unroll
    for (int it = 0; it < 2; ++it) {
      int s = it * 256 + t;
      int row = s >> 3, c = s & 7;
      const char* gsrc = (const char*)xT + (size_t)(n0 + row) * 512 + k0 * 2 + ((c ^ (row & 7)) << 4);
      async16(gsrc, smem + 32768 + (s & ~63) * 16);
    }
    __syncthreads();   // drains vmcnt -> staged data visible
    #pragma unroll
    for (int kk = 0; kk < 2; ++kk) {
      short8 a[4], b[4];
      #pragma unroll
      for (int m = 0; m < 4; ++m) {
        int row = wid * 64 + m * 16 + lrow;
        a[m] = *(const short8*)(&smem[row * 128 + (((kk * 4 + lk) ^ (row & 7)) << 4)]);
      }
      #pragma unroll
      for (int n = 0; n < 4; ++n) {
        int row = n * 16 + lrow;
        b[n] = *(const short8*)(&smem[32768 + row * 128 + (((kk * 4 + lk) ^ (row & 7)) << 4)]);
      }
      #pragma unroll
      for (int m = 0; m < 4; ++m)
        #pragma unroll
        for (int n = 0; n < 4; ++n)
          acc[m][n] = __builtin_amdgcn_mfma_f32_16x16x32_bf16(a[m], b[n], acc[m][n], 0, 0, 0);
    }
  }
  __syncthreads();

  float denp[16];
  #pragma unroll
  for (int i = 0; i < 16; ++i) denp[i] = 0.f;
  {
    const bool isk = wid < 2;
    const int base = isk ? 0 : 16384;
    #pragma unroll
    for (int m = 0; m < 4; ++m) {
      float bb[4];
      #pragma unroll
      for (int j = 0; j < 4; ++j) bb[j] = biasp[128 + wid * 64 + m * 16 + lk * 4 + j];
      #pragma unroll
      for (int n = 0; n < 4; ++n) {
        int col = n * 16 + lrow;
        int coff = col >> 3, cbyte = (col & 7) * 2;
        #pragma unroll
        for (int j = 0; j < 4; ++j) {
          int rloc = ((wid * 64) & 127) + m * 16 + lk * 4 + j;   // row within 128
          float val = acc[m][n][j] + bb[j];
          if (isk) { val = __expf(val); denp[m * 4 + j] += val; }
          *(uint16_t*)(&smem[base + rloc * 128 + ((coff ^ (rloc & 7)) << 4) + cbyte]) = f2b(val);
        }
      }
    }
  }
  __syncthreads();

  f32x4 cacc[2][2] = {};
  {
    const int h = wid;
    #pragma unroll
    for (int kw = 0; kw < 2; ++kw) {
      short8 ae[2], be[2];
      #pragma unroll
      for (int mf = 0; mf < 2; ++mf) {
        int row = h * 32 + mf * 16 + lrow;
        ae[mf] = *(const short8*)(&smem[row * 128 + (((kw * 4 + lk) ^ (row & 7)) << 4)]);
      }
      #pragma unroll
      for (int nf = 0; nf < 2; ++nf) {
        int row = h * 32 + nf * 16 + lrow;
        be[nf] = *(const short8*)(&smem[16384 + row * 128 + (((kw * 4 + lk) ^ (row & 7)) << 4)]);
      }
      #pragma unroll
      for (int mf = 0; mf < 2; ++mf)
        #pragma unroll
        for (int nf = 0; nf < 2; ++nf)
          cacc[mf][nf] = __builtin_amdgcn_mfma_f32_16x16x32_bf16(ae[mf], be[nf], cacc[mf][nf], 0, 0, 0);
    }
  }
  float* pp = part + (size_t)blockIdx.x * 4224;
  {
    float* ph = pp + wid * 1056;
    #pragma unroll
    for (int mf = 0; mf < 2; ++mf)
      #pragma unroll
      for (int nf = 0; nf < 2; ++nf)
        #pragma unroll
        for (int j = 0; j < 4; ++j) {
          int d = mf * 16 + lk * 4 + j, e = nf * 16 + lrow;
          ph[d * 32 + e] = cacc[mf][nf][j];
        }
  }
  if (wid < 2) {
    #pragma unroll
    for (int i = 0; i < 16; ++i) {
      denp[i] += __shfl_xor(denp[i], 1, 64);
      denp[i] += __shfl_xor(denp[i], 2, 64);
      denp[i] += __shfl_xor(denp[i], 4, 64);
      denp[i] += __shfl_xor(denp[i], 8, 64);
    }
    if (lrow == 0) {
      #pragma unroll
      for (int m = 0; m < 4; ++m)
        #pragma unroll
        for (int j = 0; j < 4; ++j) {
          int r = wid * 64 + m * 16 + lk * 4 + j;   // 0..127 k-row
          pp[(r >> 5) * 1056 + 1024 + (r & 31)] = denp[m * 4 + j];
        }
    }
  }
}

// ---------------------------------------------------------------------------
// K6 v2: reduce context partials over 1024 blocks, 8-way parallel over
// c-chunks.  grid 136 = 17 id-blocks x 8 chunks of 128.  Writes part2[8][4224].
__global__ __launch_bounds__(256) void k6_reduce(
    const float* __restrict__ part, float* __restrict__ part2) {
  const int bx = blockIdx.x;
  const int idb = bx % 17, cg = bx / 17;
  const int id = idb * 256 + threadIdx.x;
  if (id >= 4224) return;
  const float* p = part + (size_t)cg * 128 * 4224 + id;
  float s0 = 0.f, s1 = 0.f, s2 = 0.f, s3 = 0.f;
  for (int c = 0; c < 128; c += 4) {
    s0 += p[(size_t)(c + 0) * 4224];
    s1 += p[(size_t)(c + 1) * 4224];
    s2 += p[(size_t)(c + 2) * 4224];
    s3 += p[(size_t)(c + 3) * 4224];
  }
  part2[cg * 4224 + id] = (s0 + s1) + (s2 + s3);
}

// ---------------------------------------------------------------------------
// KM: merged M-fold + M2-fold (sums the 8 part2 chunks on load).
// grid 256, block 256.
__global__ __launch_bounds__(256) void kM_fold(
    const float* __restrict__ ow, const float* __restrict__ part2,
    const uint16_t* __restrict__ wp, const float* __restrict__ biasp,
    const float* __restrict__ ob, uint16_t* __restrict__ M2,
    float* __restrict__ bias2) {
  __shared__ float sctx[4224];
  __shared__ float sow[128];
  __shared__ float smrow[128];
  __shared__ float rb[4];
  const int o = blockIdx.x; const int t = threadIdx.x;
  for (int i = t; i < 4224; i += 256) {
    float s = 0.f;
    #pragma unroll
    for (int g = 0; g < 8; ++g) s += part2[g * 4224 + i];
    sctx[i] = s;
  }
  if (t < 128) sow[t] = ow[(size_t)o * 128 + t];
  __syncthreads();
  if (t < 128) {
    int h = t >> 5, d = t & 31;
    const float* cs = sctx + h * 1056;
    float den = cs[1024 + d];
    float s = 0.f;
    #pragma unroll
    for (int e = 0; e < 32; ++e) {
      int er = (e + d) & 31;             // rotated start: bank-conflict-free
      s += sow[h * 32 + er] * cs[d * 32 + er];
    }
    smrow[t] = s / den;
  }
  __syncthreads();
  float acc = 0.f;
  for (int d = 0; d < 128; ++d) acc += smrow[d] * b2f(wp[(size_t)d * 256 + t]);
  M2[(size_t)o * 256 + t] = f2b(acc);
  float p = (t < 128) ? smrow[t] * biasp[t] : 0.f;
  for (int m = 32; m >= 1; m >>= 1) p += __shfl_xor(p, m, 64);
  if ((t & 63) == 0) rb[t >> 6] = p;
  __syncthreads();
  if (t == 0) bias2[o] = ob[o] + rb[0] + rb[1] + rb[2] + rb[3];
}

// ---------------------------------------------------------------------------
// K7 v2: out = M2(256x256 bf16) @ xT + bias2.  BM=128, BN=128, K=256.
// Async global_load_lds staging (linear dest, pre-swizzled source).
// Output staged in two 64-row halves for 512B coalesced stores.
// grid 1024, block 256.
__global__ __launch_bounds__(256) void k7_out(
    const uint16_t* __restrict__ xT, const uint16_t* __restrict__ M2,
    const float* __restrict__ bias2, float* __restrict__ out) {
  __shared__ __align__(16) char smem[32768];
  const int t = threadIdx.x;
  const int mt = blockIdx.x & 1, nt = blockIdx.x >> 1;
  const int o0 = mt * 128, n0 = nt * 128;
  const int l = t & 63, wid = t >> 6, wr = wid >> 1, wc = wid & 1;
  const int lrow = l & 15, lk = l >> 4;

  f32x4 acc[4][4] = {};
  for (int ks = 0; ks < 4; ++ks) {
    const int k0 = ks * 64;
    __syncthreads();
    // A-slice (M2 rows o0..o0+127): 1024 slots -> LDS [0,16K)
    #pragma unroll
    for (int it = 0; it < 4; ++it) {
      int s = it * 256 + t;
      int row = s >> 3, c = s & 7;
      const char* gsrc = (const char*)M2 + (size_t)(o0 + row) * 512 + k0 * 2 + ((c ^ (row & 7)) << 4);
      async16(gsrc, smem + (s & ~63) * 16);
    }
    // B-slice (xT rows n0..n0+127): 1024 slots -> LDS [16K,32K)
    #pragma unroll
    for (int it = 0; it < 4; ++it) {
      int s = it * 256 + t;
      int row = s >> 3, c = s & 7;
      const char* gsrc = (const char*)xT + (size_t)(n0 + row) * 512 + k0 * 2 + ((c ^ (row & 7)) << 4);
      async16(gsrc, smem + 16384 + (s & ~63) * 16);
    }
    __syncthreads();
    #pragma unroll
    for (int kk = 0; kk < 2; ++kk) {
      short8 a[4], b[4];
      #pragma unroll
      for (int m = 0; m < 4; ++m) {
        int row = wr * 64 + m * 16 + lrow;
        a[m] = *(const short8*)(&smem[row * 128 + (((kk * 4 + lk) ^ (row & 7)) << 4)]);
      }
      #pragma unroll
      for (int n = 0; n < 4; ++n) {
        int row = wc * 64 + n * 16 + lrow;
        b[n] = *(const short8*)(&smem[16384 + row * 128 + (((kk * 4 + lk) ^ (row & 7)) << 4)]);
      }
      #pragma unroll
      for (int m = 0; m < 4; ++m)
        #pragma unroll
        for (int n = 0; n < 4; ++n)
          acc[m][n] = __builtin_amdgcn_mfma_f32_16x16x32_bf16(a[m], b[n], acc[m][n], 0, 0, 0);
    }
  }

  #pragma unroll
  for (int half = 0; half < 2; ++half) {
    __syncthreads();
    if (wr == half) {
      #pragma unroll
      for (int m = 0; m < 4; ++m) {
        int rb = m * 16 + lk * 4;
        float bb[4];
        #pragma unroll
        for (int j = 0; j < 4; ++j) bb[j] = bias2[o0 + half * 64 + rb + j];
        #pragma unroll
        for (int n = 0; n < 4; ++n) {
          int col = wc * 64 + n * 16 + lrow;
          #pragma unroll
          for (int j = 0; j < 4; ++j) {
            int row = rb + j;
            *(float*)(&smem[row * 512 + ((((col >> 2) ^ (row & 7)) << 4)) + (col & 3) * 4]) =
                acc[m][n][j] + bb[j];
          }
        }
      }
    }
    __syncthreads();
    #pragma unroll
    for (int p = 0; p < 8; ++p) {
      int flat = t + 256 * p; int row = flat >> 5, c = flat & 31;
      f32x4 v = *(const f32x4*)(&smem[row * 512 + (((c ^ (row & 7)) << 4))]);
      *(f32x4*)(out + (size_t)(o0 + half * 64 + row) * N_SPATIAL + n0 + c * 4) = v;
    }
  }
}

// ---------------------------------------------------------------------------
extern "C" void kernel_launch(void* const* d_in, const int* in_sizes, int n_in,
                              void* d_out, int out_size, void* d_ws, size_t ws_size,
                              hipStream_t stream) {
  const float* x   = (const float*)d_in[0];
  const float* gnw = (const float*)d_in[1];
  const float* gnb = (const float*)d_in[2];
  const float* qw  = (const float*)d_in[3];
  const float* qb  = (const float*)d_in[4];
  const float* ow  = (const float*)d_in[5];
  const float* ob  = (const float*)d_in[6];
  float* out = (float*)d_out;
  char* ws = (char*)d_ws;

  uint16_t* xT    = (uint16_t*)(ws + 0);          // 32 MB
  uint16_t* wp    = (uint16_t*)(ws + 33554432);   // 192 KB
  float*    biasp = (float*)   (ws + 33751040);   // 1.5 KB
  float*    gnp   = (float*)   (ws + 33752576);   // 256 KB
  float*    part  = (float*)   (ws + 34014720);   // 17.3 MB (1024*4224*4)
  float*    part2 = (float*)   (ws + 51316224);   // 132 KB (8*4224*4)
  uint16_t* M2    = (uint16_t*)(ws + 51451392);   // 128 KB
  float*    bias2 = (float*)   (ws + 51582464);   // 1 KB

  k1_transpose_stats<<<dim3(1024), dim3(256), 0, stream>>>(x, xT, gnp);
  k2f_fold<<<dim3(384), dim3(256), 0, stream>>>(gnp, gnw, gnb, qw, qb, wp, biasp);
  k3_kv<<<dim3(1024), dim3(256), 0, stream>>>(xT, wp, biasp, part);
  k6_reduce<<<dim3(136), dim3(256), 0, stream>>>(part, part2);
  kM_fold<<<dim3(256), dim3(256), 0, stream>>>(ow, part2, wp, biasp, ob, M2, bias2);
  k7_out<<<dim3(1024), dim3(256), 0, stream>>>(xT, M2, bias2, out);
}